// Round 5
// baseline (450.462 us; speedup 1.0000x reference)
//
#include <hip/hip_runtime.h>
#include <math.h>

typedef _Float16 f16;
typedef _Float16 f16x8 __attribute__((ext_vector_type(8)));
typedef float f32x4 __attribute__((ext_vector_type(4)));

#define HH 32
#define WW 64
#define NPX 2048
#define SLOTS 68          // 64 px + 2 halo each side
#define CHS 78336         // 36*68*32 f16 = one 32-ci slab of the halo grid
// lo-planes pre-scaled by 2^11 to stay in fp16 NORMAL range (denormal inputs
// are flushed by the MFMA pipe -- proven by earlier bit-identical failure)
#define LOSCALE 2048.0f
#define INV_LOSCALE 4.8828125e-4f

typedef const __attribute__((address_space(1))) void gvoid;
typedef __attribute__((address_space(3))) void lvoid;
__device__ __forceinline__ void gload_lds16(const void* g, void* l) {
    __builtin_amdgcn_global_load_lds((gvoid*)g, (lvoid*)l, 16, 0, 0);
}

// ---- coalesced tiled repack (device fn, runs as a block role).
// Block = (coT: 16 co) x (cic: 32 ci) x all 25 taps.
// Phase 1: 16 contiguous 800-float runs -> LDS via wave-flat float4 (coalesced;
//          old repack read 4B at 100B lane stride, 25x re-touch through L3).
// Phase 2: mask + split-f16 from LDS, coalesced writes to tiled WP layout:
//          dst = ((tap*nCoT + coT)*nCic + cic)*512 + co16*32 + ci32.
// Bit-identical WP content to the old repack_kernel.
__device__ __forceinline__ void repack_tile(
    const float* __restrict__ W, f16* __restrict__ WP, float* RAWF,
    int Cin, int nCoT, int nCic, int cpg_in_log2, int limb, int is_out,
    int coT, int cic, int plane)
{
    const int nt = blockDim.x, t = threadIdx.x;
    const int co0 = coT * 16, ci0 = cic * 32;
    for (int u = t; u < 3200; u += nt) {          // 12800 floats as float4
        int co16 = u / 200, j4 = u - co16 * 200;
        int co_p = co0 + co16;
        int co_orig = is_out ? 3 * (co_p >> 1) + 1 + (co_p & 1) : co_p;
        float4 v = *(const float4*)(W + (size_t)(co_orig * Cin + ci0) * 25 + j4 * 4);
        *(float4*)&RAWF[co16 * 800 + j4 * 4] = v;
    }
    __syncthreads();
    const int base = (coT * nCic + cic) * 512;
    const int tapStride = nCoT * nCic * 512;
    for (int e = t; e < 12800; e += nt) {
        int tap = e >> 9, r = e & 511;
        int co16 = r >> 5, ci32 = r & 31;
        int ky = tap / 5, kx = tap - 5 * ky;
        int co_p = co0 + co16;
        int g_out = is_out ? (co_p >> 1) : (co_p >> 2);
        int g_in = (ci0 + ci32) >> cpg_in_log2;
        float v = 0.f;
        if (ky + kx <= limb + g_out - g_in)
            v = RAWF[co16 * 800 + ci32 * 25 + tap];
        f16 vh = (f16)v;
        int dst = base + tap * tapStride + co16 * 32 + ci32;
        WP[dst] = vh;
        WP[plane + dst] = (f16)((v - (float)vh) * LOSCALE);
    }
}

// ---- init dispatch: role-split blocks. [0,1224): zero P|Q (int4);
// [1224,1836): prep X0 incl halo (both planes; halo rows/cols -> 0);
// [1836,1868): repack w_in -> WP (32 blocks: 16 coT x 2 cic).
__global__ __launch_bounds__(256) void init_kernel(
    const float* __restrict__ data, const float* __restrict__ mask,
    f16* __restrict__ PQ, f16* __restrict__ X0,
    const float* __restrict__ w_in, f16* __restrict__ WP)
{
    __shared__ __align__(16) float RAWF[12800];
    const int b = blockIdx.x, t = threadIdx.x;
    if (b < 1224) {
        *(int4*)(PQ + (size_t)(b * 256 + t) * 8) = make_int4(0, 0, 0, 0);
    } else if (b < 1836) {
        int e = (b - 1224) * 256 + t;          // [0, 156672): si*64 + ci
        int si = e >> 6, ci = e & 63;
        int row = si / 68, slot = si - row * 68;
        float v = 0.f;
        if (row >= 2 && row < 34 && slot >= 2 && slot < 66) {
            int px = (row - 2) * 64 + (slot - 2);
            v = (data[ci * NPX + px] - 3.5f) * mask[ci * NPX + px];
        }
        int dst = (ci >> 5) * CHS + si * 32 + (ci & 31);
        X0[dst] = (f16)v;
        X0[156672 + dst] = (f16)0.f;
    } else {
        int rb = b - 1836;
        repack_tile(w_in, WP, RAWF, 64, 16, 2, 0, 3, 0, rb >> 1, rb & 1, 409600);
    }
}

// ---- fused conv V6 = V5 conv (unchanged) + fused next-layer repack blocks.
// Conv: 16co x 64px per wave (1x4 frags of mfma_f32_16x16x32_f16), ky-per-wave
// (5 waves), single-buffered LDS stage via global_load_lds, 2 blocks/CU,
// complementary (mt, nmt-1-mt) pairing, XCD-affinity decode (pair = blkIdx&7),
// kx0-A hoist before the staging barrier.
// Blocks >= nConv run repack_tile for the NEXT layer's weights into the other
// WP buffer (ping-pong) -- independent work, hides under the conv.
__global__ __launch_bounds__(320, 3) void conv_kernel(
    const f16* __restrict__ IN, int Cin, int inPlane,
    const f16* __restrict__ WP, int wPlane,
    const float* __restrict__ bias,
    const f16* __restrict__ RES, int resPlane,
    f16* __restrict__ OA, int oaPlane,
    float* __restrict__ OT,
    int nmt, int Coutp, int cpg_out, int cpg_in, int limb, int mode,
    const float* __restrict__ rW, f16* __restrict__ rWP,
    int rCin, int rnCoT, int rnCic, int rcpg_in_log2, int rlimb, int ris_out,
    int rplane, int nConv)
{
    __shared__ __align__(16) char SMEM[51200];   // conv uses 46080; repack 51200
    f16* BL = (f16*)SMEM;      // [plane2][row5][slot68][ci32] = 43520 B (+pad)
    float* RED = (float*)SMEM; // [kw5][px64][co pad20] = 25600 B (after K loop)

    if (blockIdx.x >= (unsigned)nConv) {         // repack role (block-uniform)
        int rb = blockIdx.x - nConv;
        repack_tile(rW, rWP, (float*)SMEM, rCin, rnCoT, rnCic,
                    rcpg_in_log2, rlimb, ris_out, rb / rnCic, rb % rnCic, rplane);
        return;
    }

    const int t = threadIdx.x;
    const int kw = t >> 6;                 // wave index == ky
    const int lane = t & 63, l15 = lane & 15, q = lane >> 4;

    // XCD-affinity decode: pairIdx rides the low 3 bits (HW XCD round-robin).
    const int b = blockIdx.x;
    const int p3 = b & 7, r = b >> 3;
    int pairIdx, slot, h_;
    if (nmt == 16) { pairIdx = p3;     h_ = r & 31; slot = r >> 5; }
    else           { pairIdx = p3 & 3; h_ = r;      slot = p3 >> 2; }
    const int h = h_;
    const int mt = slot ? (nmt - 1 - pairIdx) : pairIdx;
    const int co0 = mt * 16;
    const int g_max = (co0 + 15) / cpg_out;

    // masked K-extent per kx for this wave's ky (allowed iff ky+kx<=limb+g_out-g_in)
    int cnt[5];
#pragma unroll
    for (int kx = 0; kx < 5; kx++) {
        int c = (g_max + limb - (kw + kx) + 1) * cpg_in;
        c = c < Cin ? c : Cin;
        cnt[kx] = c > 0 ? c : 0;
    }
    int ci_top = (g_max + limb + 1) * cpg_in;   // block-uniform chunk bound
    ci_top = ci_top < Cin ? ci_top : Cin;

    // per-lane staging sources: 2720 16B-units, linear in [pl][row5][slot68][ci32]
    const f16* src[9];
#pragma unroll
    for (int rr = 0; rr < 9; rr++) {
        int u = rr * 320 + t;
        if (u >= 2720) u = 0;              // tail lanes: any valid addr (dest=pad)
        int pl = u >= 1360 ? 1 : 0;
        int rem = u - pl * 1360;
        src[rr] = IN + (size_t)pl * inPlane + h * 2176 + rem * 8;
    }

    f32x4 acc_h[4], acc_m[4];
#pragma unroll
    for (int j = 0; j < 4; j++) {
        acc_h[j] = (f32x4){0.f, 0.f, 0.f, 0.f};
        acc_m[j] = (f32x4){0.f, 0.f, 0.f, 0.f};
    }

    // tiled weight addressing: tile (tap, mt, cic) is 512 f16 contiguous
    const size_t kxs = (size_t)Coutp * Cin;            // per-kx tap stride
    const f16* wb0 = WP + (size_t)(kw * 5 * (Coutp >> 4) + mt) * ((size_t)Cin << 4)
                   + l15 * 32 + q * 8;

    int coff = 0;                                      // (ci0/32)*CHS
    for (int ci0 = 0; ci0 < ci_top; ci0 += 32, coff += CHS) {
        __syncthreads();
        // stage B: 43520 B = 9 rounds x 5 waves x 1024 B, direct global->LDS
#pragma unroll
        for (int rr = 0; rr < 9; rr++) {
            int ub = rr * 320 + kw * 64;
            if (ub < 2720)                 // wave-uniform (BL padded for overshoot)
                gload_lds16(src[rr] + coff, BL + ub * 8);
        }
        // kx=0 A-frags issued BEFORE the barrier: latency overlaps stage drain
        const f16* wb = wb0 + (ci0 >> 5) * 512;
        f16x8 cah, cal, nah, nal;
        if (ci0 < cnt[0]) {
            cah = *(const f16x8*)(wb);
            cal = *(const f16x8*)(wb + wPlane);
        }
        __syncthreads();

#pragma unroll
        for (int kx = 0; kx < 5; kx++) {
            if (ci0 >= cnt[kx]) break;     // cnt non-increasing in kx, wave-uniform
            if (kx < 4 && ci0 < cnt[kx + 1]) {
                nah = *(const f16x8*)(wb + (kx + 1) * kxs);
                nal = *(const f16x8*)(wb + (kx + 1) * kxs + wPlane);
            }
            f16x8 bh[4], bl[4];
#pragma unroll
            for (int j = 0; j < 4; j++) {
                int slt = j * 16 + l15 + kx;
                bh[j] = *(const f16x8*)&BL[(0 * 5 + kw) * (SLOTS * 32) + slt * 32 + q * 8];
                bl[j] = *(const f16x8*)&BL[(1 * 5 + kw) * (SLOTS * 32) + slt * 32 + q * 8];
            }
#pragma unroll
            for (int j = 0; j < 4; j++) {
                acc_h[j] = __builtin_amdgcn_mfma_f32_16x16x32_f16(cah, bh[j], acc_h[j], 0, 0, 0);
                acc_m[j] = __builtin_amdgcn_mfma_f32_16x16x32_f16(cah, bl[j], acc_m[j], 0, 0, 0);
                acc_m[j] = __builtin_amdgcn_mfma_f32_16x16x32_f16(cal, bh[j], acc_m[j], 0, 0, 0);
            }
            cah = nah; cal = nal;
        }
    }

    // in-block ky reduction through LDS (C/D layout: px=j*16+l15, co=q*4+r)
    __syncthreads();   // all BL reads done before RED aliases SMEM
#pragma unroll
    for (int j = 0; j < 4; j++) {
        f32x4 v;
#pragma unroll
        for (int rr = 0; rr < 4; rr++)
            v[rr] = acc_h[j][rr] + acc_m[j][rr] * INV_LOSCALE;
        *(f32x4*)&RED[(kw * 64 + j * 16 + l15) * 20 + q * 4] = v;
    }
    __syncthreads();

    if (mode == 0) {
        // bias + relu (+ residual) -> split-f16 halo store (chunk-major layout)
        for (int c = t; c < 1024; c += 320) {
            int px = c >> 4, col = c & 15;
            float v = bias[co0 + col];
#pragma unroll
            for (int k5 = 0; k5 < 5; k5++) v += RED[(k5 * 64 + px) * 20 + col];
            v = fmaxf(v, 0.f);
            int cc = co0 + col;
            int o = (cc >> 5) * CHS + ((h + 2) * SLOTS + px + 2) * 32 + (cc & 31);
            if (RES) v += (float)RES[o] + (float)RES[resPlane + o] * INV_LOSCALE;
            f16 vh = (f16)v;
            OA[o] = vh;
            OA[oaPlane + o] = (f16)((v - (float)vh) * LOSCALE);
        }
    } else {
        // output conv: co_p = g*2 + {mu,sig}; fold bias+softplus+erf table here
        for (int c = t; c < 1024; c += 320) {
            int px = c >> 4, col = c & 15;
            float v = bias[3 * ((co0 + col) >> 1) + 1 + (col & 1)];
#pragma unroll
            for (int k5 = 0; k5 < 5; k5++) v += RED[(k5 * 64 + px) * 20 + col];
            RED[px * 20 + col] = v;    // own-cell write after own-cell reads: safe
        }
        __syncthreads();
        for (int c = t; c < 512; c += 320) {
            int px = c >> 3, gl = c & 7;
            float mu = RED[px * 20 + 2 * gl];
            float s  = RED[px * 20 + 2 * gl + 1];
            float sp = fmaxf(s, 0.f) + log1pf(expf(-fabsf(s)));
            float sig = sp + 1e-6f;
            float inv = 1.f / (sig * 1.41421356237f);
            int g = (co0 >> 1) + gl;
            float* o = OT + ((size_t)g * NPX + h * WW + px) * 8;
#pragma unroll
            for (int k = 0; k < 8; k++) {
                float z = ((float)k - 3.0f - mu) * inv;
                o[k] = 32768.f * (1.f + erff(z));
            }
        }
    }
}

extern "C" void kernel_launch(void* const* d_in, const int* in_sizes, int n_in,
                              void* d_out, int out_size, void* d_ws, size_t ws_size,
                              hipStream_t stream) {
    const float* data  = (const float*)d_in[0];
    const float* mask  = (const float*)d_in[1];
    const float* w_in  = (const float*)d_in[2];
    const float* b_in  = (const float*)d_in[3];
    const float* w_hid = (const float*)d_in[4];
    const float* b_hid = (const float*)d_in[5];
    const float* w_out = (const float*)d_in[6];
    const float* b_out = (const float*)d_in[7];
    float* out = (float*)d_out;

    // ws: WPA 6.55MB | WPB 6.55 | P 2.51 | Q 2.51 | X0 0.63 = 18.75 MB
    f16* WPA = (f16*)d_ws;                 // ping-pong weight buffers
    f16* WPB = WPA + 3276800;
    f16* P   = WPB + 3276800;              // 2 x 8*CHS f16 (halo act, x)
    f16* Q   = P + 1253376;                // 2 x 8*CHS f16 (halo act, h1)
    f16* X0  = Q + 1253376;                // 2 x 2*CHS f16

    // init: zero P|Q (1224 blk) + prep X0 incl halo (612) + repack w_in (32)
    init_kernel<<<1868, 256, 0, stream>>>(data, mask, P, X0, w_in, WPA);

    f16* cur = WPA;
    f16* nxt = WPB;

    // c0: input conv X0->P (Cin=64, strict limb=3) + fused repack of w_hid[0]
    conv_kernel<<<640, 320, 0, stream>>>(X0, 64, 156672, cur, 409600,
        b_in, nullptr, 0, P, 626688, nullptr, 16, 256, 4, 1, 3, 0,
        w_hid, nxt, 256, 16, 8, 2, 4, 0, 1638400, 512);
    { f16* tmp = cur; cur = nxt; nxt = tmp; }

    // c1..c10: hidden convs; ck uses h_{k-1}, fused repack of h_k (k<10) or
    // w_out (k==10). odd k: P->Q; even k: Q->P with residual P.
    for (int k = 1; k <= 10; ++k) {
        const int isLast = (k == 10);
        const float* rw = isLast ? w_out : (w_hid + (size_t)k * 1638400);
        const int rgrid = isLast ? 64 : 128;
        const int rnCoT = isLast ? 8 : 16;
        const int ris   = isLast ? 1 : 0;
        const int rpl   = isLast ? 819200 : 1638400;
        if (k & 1)
            conv_kernel<<<512 + rgrid, 320, 0, stream>>>(P, 256, 626688, cur, 1638400,
                b_hid + (size_t)(k - 1) * 256, nullptr, 0, Q, 626688, nullptr,
                16, 256, 4, 4, 4, 0,
                rw, nxt, 256, rnCoT, 8, 2, 4, ris, rpl, 512);
        else
            conv_kernel<<<512 + rgrid, 320, 0, stream>>>(Q, 256, 626688, cur, 1638400,
                b_hid + (size_t)(k - 1) * 256, P, 626688, P, 626688, nullptr,
                16, 256, 4, 4, 4, 0,
                rw, nxt, 256, rnCoT, 8, 2, 4, ris, rpl, 512);
        f16* tmp = cur; cur = nxt; nxt = tmp;
    }

    // c11: output conv (mu/sig only, Coutp=128, cpg_out=2, limb=4) + erf table
    conv_kernel<<<256, 320, 0, stream>>>(P, 256, 626688, cur, 819200,
        b_out, nullptr, 0, nullptr, 0, out, 8, 128, 2, 4, 4, 1,
        nullptr, nullptr, 256, 8, 1, 2, 4, 0, 0, 256);
}

// Round 6
// 424.527 us; speedup vs baseline: 1.0611x; 1.0611x over previous
//
#include <hip/hip_runtime.h>
#include <math.h>

typedef _Float16 f16;
typedef _Float16 f16x8 __attribute__((ext_vector_type(8)));
typedef float f32x4 __attribute__((ext_vector_type(4)));

#define HH 32
#define WW 64
#define NPX 2048
#define SLOTS 68          // 64 px + 2 halo each side
#define CHS 78336         // 36*68*32 f16 = one 32-ci slab of the halo grid
// lo-planes pre-scaled by 2^11 to stay in fp16 NORMAL range (denormal inputs
// are flushed by the MFMA pipe -- proven by earlier bit-identical failure)
#define LOSCALE 2048.0f
#define INV_LOSCALE 4.8828125e-4f

typedef const __attribute__((address_space(1))) void gvoid;
typedef __attribute__((address_space(3))) void lvoid;
__device__ __forceinline__ void gload_lds16(const void* g, void* l) {
    __builtin_amdgcn_global_load_lds((gvoid*)g, (lvoid*)l, 16, 0, 0);
}

// ---- coalesced tiled repack (device fn, runs as a block role).
// Block = (coT: 16 co) x (cic: 32 ci) x all 25 taps. Bit-identical WP content.
__device__ __forceinline__ void repack_tile(
    const float* __restrict__ W, f16* __restrict__ WP, float* RAWF,
    int Cin, int nCoT, int nCic, int cpg_in_log2, int limb, int is_out,
    int coT, int cic, int plane)
{
    const int nt = blockDim.x, t = threadIdx.x;
    const int co0 = coT * 16, ci0 = cic * 32;
    for (int u = t; u < 3200; u += nt) {          // 12800 floats as float4
        int co16 = u / 200, j4 = u - co16 * 200;
        int co_p = co0 + co16;
        int co_orig = is_out ? 3 * (co_p >> 1) + 1 + (co_p & 1) : co_p;
        float4 v = *(const float4*)(W + (size_t)(co_orig * Cin + ci0) * 25 + j4 * 4);
        *(float4*)&RAWF[co16 * 800 + j4 * 4] = v;
    }
    __syncthreads();
    const int base = (coT * nCic + cic) * 512;
    const int tapStride = nCoT * nCic * 512;
    for (int e = t; e < 12800; e += nt) {
        int tap = e >> 9, r = e & 511;
        int co16 = r >> 5, ci32 = r & 31;
        int ky = tap / 5, kx = tap - 5 * ky;
        int co_p = co0 + co16;
        int g_out = is_out ? (co_p >> 1) : (co_p >> 2);
        int g_in = (ci0 + ci32) >> cpg_in_log2;
        float v = 0.f;
        if (ky + kx <= limb + g_out - g_in)
            v = RAWF[co16 * 800 + ci32 * 25 + tap];
        f16 vh = (f16)v;
        int dst = base + tap * tapStride + co16 * 32 + ci32;
        WP[dst] = vh;
        WP[plane + dst] = (f16)((v - (float)vh) * LOSCALE);
    }
}

// ---- init dispatch: role-split blocks. [0,1224): zero P|Q (int4);
// [1224,1836): prep X0 incl halo; [1836,1868): repack w_in -> WP.
__global__ __launch_bounds__(256) void init_kernel(
    const float* __restrict__ data, const float* __restrict__ mask,
    f16* __restrict__ PQ, f16* __restrict__ X0,
    const float* __restrict__ w_in, f16* __restrict__ WP)
{
    __shared__ __align__(16) float RAWF[12800];
    const int b = blockIdx.x, t = threadIdx.x;
    if (b < 1224) {
        *(int4*)(PQ + (size_t)(b * 256 + t) * 8) = make_int4(0, 0, 0, 0);
    } else if (b < 1836) {
        int e = (b - 1224) * 256 + t;          // [0, 156672): si*64 + ci
        int si = e >> 6, ci = e & 63;
        int row = si / 68, slot = si - row * 68;
        float v = 0.f;
        if (row >= 2 && row < 34 && slot >= 2 && slot < 66) {
            int px = (row - 2) * 64 + (slot - 2);
            v = (data[ci * NPX + px] - 3.5f) * mask[ci * NPX + px];
        }
        int dst = (ci >> 5) * CHS + si * 32 + (ci & 31);
        X0[dst] = (f16)v;
        X0[156672 + dst] = (f16)0.f;
    } else {
        int rb = b - 1836;
        repack_tile(w_in, WP, RAWF, 64, 16, 2, 0, 3, 0, rb >> 1, rb & 1, 409600);
    }
}

// ---- fused conv V7: BARRIER-FREE per-wave staging.
// Wave kw reads ONLY LDS rows (plane0,kw)/(plane1,kw) -> each wave stages its
// OWN rows into a private 9216B region (9 x 1KB gload_lds rounds) and syncs on
// its OWN counters: vmcnt(0) before compute (its 9 gloads + hoisted kx0 A),
// lgkmcnt(0) before issuing next chunk's overwriting gloads (own ds_reads
// complete; ~free since MFMAs already forced them). NO __syncthreads in the
// K loop -- the 10 free-running waves/CU hide each other's stage + A latency,
// removing the per-chunk all-wave vmcnt(0) convoy (the ~20us/conv gap between
// pipe-sum ~10us and measured ~31us). LDS values/MFMA order bit-identical.
// Everything else = V6: 16co x 64px per wave, complementary (mt,nmt-1-mt)
// pairing, XCD-affinity decode (pair = blkIdx&7), tiled weights, fused repack.
__global__ __launch_bounds__(320, 3) void conv_kernel(
    const f16* __restrict__ IN, int Cin, int inPlane,
    const f16* __restrict__ WP, int wPlane,
    const float* __restrict__ bias,
    const f16* __restrict__ RES, int resPlane,
    f16* __restrict__ OA, int oaPlane,
    float* __restrict__ OT,
    int nmt, int Coutp, int cpg_out, int cpg_in, int limb, int mode,
    const float* __restrict__ rW, f16* __restrict__ rWP,
    int rCin, int rnCoT, int rnCic, int rcpg_in_log2, int rlimb, int ris_out,
    int rplane, int nConv)
{
    __shared__ __align__(16) char SMEM[51200];   // conv: 46080; repack: 51200
    f16* BL = (f16*)SMEM;      // [wave5][pl0 row 4352B | pl1 row 4352B | pad 512]
    float* RED = (float*)SMEM; // [kw5][px64][co pad20] = 25600 B (after K loop)

    if (blockIdx.x >= (unsigned)nConv) {         // repack role (block-uniform)
        int rb = blockIdx.x - nConv;
        repack_tile(rW, rWP, (float*)SMEM, rCin, rnCoT, rnCic,
                    rcpg_in_log2, rlimb, ris_out, rb / rnCic, rb % rnCic, rplane);
        return;
    }

    const int t = threadIdx.x;
    const int kw = t >> 6;                 // wave index == ky
    const int lane = t & 63, l15 = lane & 15, q = lane >> 4;

    // XCD-affinity decode: pairIdx rides the low 3 bits (HW XCD round-robin).
    const int b = blockIdx.x;
    const int p3 = b & 7, r = b >> 3;
    int pairIdx, slot, h_;
    if (nmt == 16) { pairIdx = p3;     h_ = r & 31; slot = r >> 5; }
    else           { pairIdx = p3 & 3; h_ = r;      slot = p3 >> 2; }
    const int h = h_;
    const int mt = slot ? (nmt - 1 - pairIdx) : pairIdx;
    const int co0 = mt * 16;
    const int g_max = (co0 + 15) / cpg_out;

    // masked K-extent per kx for this wave's ky (allowed iff ky+kx<=limb+g_out-g_in)
    int cnt[5];
#pragma unroll
    for (int kx = 0; kx < 5; kx++) {
        int c = (g_max + limb - (kw + kx) + 1) * cpg_in;
        c = c < Cin ? c : Cin;
        cnt[kx] = c > 0 ? c : 0;
    }
    int ci_top = (g_max + limb + 1) * cpg_in;   // block-uniform chunk bound
    ci_top = ci_top < Cin ? ci_top : Cin;
    const int NT = (ci_top + 31) >> 5;

    // per-lane staging source offsets for THIS WAVE's rows (f16 units).
    // unit u in [0,544): pl = u>=272, rem covers [slot68][ci32] of row h+kw.
    // round r covers u = r*64 + lane; r=8 lanes>=32 are pad (clamped source).
    int soff[9];
    const int rowg = (h + kw) * 2176;
#pragma unroll
    for (int r9 = 0; r9 < 9; ++r9) {
        int u = r9 * 64 + lane;
        if (u > 543) u = 543;
        int pl = u >= 272 ? 1 : 0;
        int rem = u - (pl ? 272 : 0);
        soff[r9] = pl * inPlane + rowg + rem * 8;
    }
    // wave-private LDS region: 576 16B-units = 4608 f16
    f16* const wreg = BL + kw * 4608;

    f32x4 acc_h[4], acc_m[4];
#pragma unroll
    for (int j = 0; j < 4; j++) {
        acc_h[j] = (f32x4){0.f, 0.f, 0.f, 0.f};
        acc_m[j] = (f32x4){0.f, 0.f, 0.f, 0.f};
    }

    // tiled weight addressing: tile (tap, mt, cic) is 512 f16 contiguous
    const size_t kxs = (size_t)Coutp * Cin;            // per-kx tap stride
    const f16* wb0 = WP + (size_t)(kw * 5 * (Coutp >> 4) + mt) * ((size_t)Cin << 4)
                   + l15 * 32 + q * 8;

    // prologue: stage chunk 0 (own rows only)
#pragma unroll
    for (int r9 = 0; r9 < 9; ++r9)
        gload_lds16(IN + soff[r9], wreg + r9 * 512);

    for (int it = 0; it < NT; ++it) {
        const int ci0 = it << 5;
        // kx=0 A-frags issued BEFORE the wait: latency overlaps the stage drain
        const f16* wb = wb0 + it * 512;
        f16x8 cah, cal, nah, nal;
        if (ci0 < cnt[0]) {
            cah = *(const f16x8*)(wb);
            cal = *(const f16x8*)(wb + wPlane);
        }
        asm volatile("s_waitcnt vmcnt(0)" ::: "memory");   // own stage landed

        const f16* bhp = wreg + q * 8;          // [slot68][ci32], plane0
        const f16* blp = bhp + 2176;            // plane1
#pragma unroll
        for (int kx = 0; kx < 5; kx++) {
            if (ci0 >= cnt[kx]) break;          // per-wave now: barrier-free
            if (kx < 4 && ci0 < cnt[kx + 1]) {
                nah = *(const f16x8*)(wb + (kx + 1) * kxs);
                nal = *(const f16x8*)(wb + (kx + 1) * kxs + wPlane);
            }
            f16x8 bh[4], bl[4];
#pragma unroll
            for (int j = 0; j < 4; j++) {
                int slt = j * 16 + l15 + kx;
                bh[j] = *(const f16x8*)(bhp + slt * 32);
                bl[j] = *(const f16x8*)(blp + slt * 32);
            }
#pragma unroll
            for (int j = 0; j < 4; j++) {
                acc_h[j] = __builtin_amdgcn_mfma_f32_16x16x32_f16(cah, bh[j], acc_h[j], 0, 0, 0);
                acc_m[j] = __builtin_amdgcn_mfma_f32_16x16x32_f16(cah, bl[j], acc_m[j], 0, 0, 0);
                acc_m[j] = __builtin_amdgcn_mfma_f32_16x16x32_f16(cal, bh[j], acc_m[j], 0, 0, 0);
            }
            cah = nah; cal = nal;
        }
        if (it + 1 < NT) {
            // own ds_reads complete (MFMAs forced them) -> safe to overwrite
            asm volatile("s_waitcnt lgkmcnt(0)" ::: "memory");
            const int coff = (it + 1) * CHS;
#pragma unroll
            for (int r9 = 0; r9 < 9; ++r9)
                gload_lds16(IN + soff[r9] + coff, wreg + r9 * 512);
        }
    }

    // in-block ky reduction through LDS (C/D layout: px=j*16+l15, co=q*4+r)
    __syncthreads();   // drains ALL waves' loads/reads before RED aliases SMEM
#pragma unroll
    for (int j = 0; j < 4; j++) {
        f32x4 v;
#pragma unroll
        for (int rr = 0; rr < 4; rr++)
            v[rr] = acc_h[j][rr] + acc_m[j][rr] * INV_LOSCALE;
        *(f32x4*)&RED[(kw * 64 + j * 16 + l15) * 20 + q * 4] = v;
    }
    __syncthreads();

    if (mode == 0) {
        // bias + relu (+ residual) -> split-f16 halo store (chunk-major layout)
        for (int c = t; c < 1024; c += 320) {
            int px = c >> 4, col = c & 15;
            float v = bias[co0 + col];
#pragma unroll
            for (int k5 = 0; k5 < 5; k5++) v += RED[(k5 * 64 + px) * 20 + col];
            v = fmaxf(v, 0.f);
            int cc = co0 + col;
            int o = (cc >> 5) * CHS + ((h + 2) * SLOTS + px + 2) * 32 + (cc & 31);
            if (RES) v += (float)RES[o] + (float)RES[resPlane + o] * INV_LOSCALE;
            f16 vh = (f16)v;
            OA[o] = vh;
            OA[oaPlane + o] = (f16)((v - (float)vh) * LOSCALE);
        }
    } else {
        // output conv: co_p = g*2 + {mu,sig}; fold bias+softplus+erf table here
        for (int c = t; c < 1024; c += 320) {
            int px = c >> 4, col = c & 15;
            float v = bias[3 * ((co0 + col) >> 1) + 1 + (col & 1)];
#pragma unroll
            for (int k5 = 0; k5 < 5; k5++) v += RED[(k5 * 64 + px) * 20 + col];
            RED[px * 20 + col] = v;    // own-cell write after own-cell reads: safe
        }
        __syncthreads();
        for (int c = t; c < 512; c += 320) {
            int px = c >> 3, gl = c & 7;
            float mu = RED[px * 20 + 2 * gl];
            float s  = RED[px * 20 + 2 * gl + 1];
            float sp = fmaxf(s, 0.f) + log1pf(expf(-fabsf(s)));
            float sig = sp + 1e-6f;
            float inv = 1.f / (sig * 1.41421356237f);
            int g = (co0 >> 1) + gl;
            float* o = OT + ((size_t)g * NPX + h * WW + px) * 8;
#pragma unroll
            for (int k = 0; k < 8; k++) {
                float z = ((float)k - 3.0f - mu) * inv;
                o[k] = 32768.f * (1.f + erff(z));
            }
        }
    }
}

extern "C" void kernel_launch(void* const* d_in, const int* in_sizes, int n_in,
                              void* d_out, int out_size, void* d_ws, size_t ws_size,
                              hipStream_t stream) {
    const float* data  = (const float*)d_in[0];
    const float* mask  = (const float*)d_in[1];
    const float* w_in  = (const float*)d_in[2];
    const float* b_in  = (const float*)d_in[3];
    const float* w_hid = (const float*)d_in[4];
    const float* b_hid = (const float*)d_in[5];
    const float* w_out = (const float*)d_in[6];
    const float* b_out = (const float*)d_in[7];
    float* out = (float*)d_out;

    // ws: WPA 6.55MB | WPB 6.55 | P 2.51 | Q 2.51 | X0 0.63 = 18.75 MB
    f16* WPA = (f16*)d_ws;                 // ping-pong weight buffers
    f16* WPB = WPA + 3276800;
    f16* P   = WPB + 3276800;              // 2 x 8*CHS f16 (halo act, x)
    f16* Q   = P + 1253376;                // 2 x 8*CHS f16 (halo act, h1)
    f16* X0  = Q + 1253376;                // 2 x 2*CHS f16

    // init: zero P|Q (1224 blk) + prep X0 incl halo (612) + repack w_in (32)
    init_kernel<<<1868, 256, 0, stream>>>(data, mask, P, X0, w_in, WPA);

    f16* cur = WPA;
    f16* nxt = WPB;

    // c0: input conv X0->P (Cin=64, strict limb=3) + fused repack of w_hid[0]
    conv_kernel<<<640, 320, 0, stream>>>(X0, 64, 156672, cur, 409600,
        b_in, nullptr, 0, P, 626688, nullptr, 16, 256, 4, 1, 3, 0,
        w_hid, nxt, 256, 16, 8, 2, 4, 0, 1638400, 512);
    { f16* tmp = cur; cur = nxt; nxt = tmp; }

    // c1..c10: hidden convs; ck uses h_{k-1}, fused repack of h_k (k<10) or
    // w_out (k==10). odd k: P->Q; even k: Q->P with residual P.
    for (int k = 1; k <= 10; ++k) {
        const int isLast = (k == 10);
        const float* rw = isLast ? w_out : (w_hid + (size_t)k * 1638400);
        const int rgrid = isLast ? 64 : 128;
        const int rnCoT = isLast ? 8 : 16;
        const int ris   = isLast ? 1 : 0;
        const int rpl   = isLast ? 819200 : 1638400;
        if (k & 1)
            conv_kernel<<<512 + rgrid, 320, 0, stream>>>(P, 256, 626688, cur, 1638400,
                b_hid + (size_t)(k - 1) * 256, nullptr, 0, Q, 626688, nullptr,
                16, 256, 4, 4, 4, 0,
                rw, nxt, 256, rnCoT, 8, 2, 4, ris, rpl, 512);
        else
            conv_kernel<<<512 + rgrid, 320, 0, stream>>>(Q, 256, 626688, cur, 1638400,
                b_hid + (size_t)(k - 1) * 256, P, 626688, P, 626688, nullptr,
                16, 256, 4, 4, 4, 0,
                rw, nxt, 256, rnCoT, 8, 2, 4, ris, rpl, 512);
        f16* tmp = cur; cur = nxt; nxt = tmp;
    }

    // c11: output conv (mu/sig only, Coutp=128, cpg_out=2, limb=4) + erf table
    conv_kernel<<<256, 320, 0, stream>>>(P, 256, 626688, cur, 819200,
        b_out, nullptr, 0, nullptr, 0, out, 8, 128, 2, 4, 4, 1,
        nullptr, nullptr, 256, 8, 1, 2, 4, 0, 0, 256);
}